// Round 1
// baseline (145.107 us; speedup 1.0000x reference)
//
#include <hip/hip_runtime.h>
#include <hip/hip_bf16.h>

typedef __bf16 bf16x8 __attribute__((ext_vector_type(8)));
typedef float  f32x4  __attribute__((ext_vector_type(4)));

#define MFMA16(acc, a, b) acc = __builtin_amdgcn_mfma_f32_16x16x32_bf16(a, b, acc, 0, 0, 0)

__device__ __forceinline__ bf16x8 cvt8(float4 a, float4 b) {
  bf16x8 r;
  r[0] = (__bf16)a.x; r[1] = (__bf16)a.y; r[2] = (__bf16)a.z; r[3] = (__bf16)a.w;
  r[4] = (__bf16)b.x; r[5] = (__bf16)b.y; r[6] = (__bf16)b.z; r[7] = (__bf16)b.w;
  return r;
}

// Reorder W1 [128][64] and W2 [64][64] (fp32, row-major) into MFMA B-fragment
// order, bf16, in workspace:
//   W1frag: [ks=4][nt=4][lane=64][j=8]  value = W1[ks*32 + (lane>>4)*8 + j][nt*16 + (lane&15)]
//   W2frag: [ks=2][nt=4][lane=64][j=8]  value = W2[ks*32 + (lane>>4)*8 + j][nt*16 + (lane&15)]
__global__ void prep_frags(const float* __restrict__ W1,
                           const float* __restrict__ W2,
                           __bf16* __restrict__ wf) {
  int idx = blockIdx.x * 256 + threadIdx.x;
  if (idx < 8192) {
    int j = idx & 7, lane = (idx >> 3) & 63, nt = (idx >> 9) & 3, ks = idx >> 11;
    int i = ks * 32 + ((lane >> 4) << 3) + j;
    int col = nt * 16 + (lane & 15);
    wf[idx] = (__bf16)W1[i * 64 + col];
  } else if (idx < 12288) {
    int t = idx - 8192;
    int j = t & 7, lane = (t >> 3) & 63, nt = (t >> 9) & 3, ks = (t >> 11) & 1;
    int i = ks * 32 + ((lane >> 4) << 3) + j;
    int col = nt * 16 + (lane & 15);
    wf[idx] = (__bf16)W2[i * 64 + col];
  }
}

// One wave per node. 512 threads = 8 waves per block.
// LDS: [0,16384)   W1frag bf16
//      [16384,24576) W2frag bf16
//      [24576 + wid*4096) H1 tile 32x64 bf16, XOR-swizzled 16B chunks
//      [57344 + wid*128)  att broadcast (32 f32)
__global__ __launch_bounds__(512) void graph_agg(
    const float* __restrict__ emb,
    const float* __restrict__ b1g,
    const float* __restrict__ b2g,
    const float* __restrict__ w3g,
    const float* __restrict__ b3g,
    const int* __restrict__ video_nodes,
    const int* __restrict__ neigh_idx,
    const int* __restrict__ neigh_deg,
    const __bf16* __restrict__ wf,
    float* __restrict__ out,
    int N) {
  __shared__ __align__(16) unsigned char smem[58368];

  // Stage weight fragments (24576 B) into LDS, coalesced.
  {
    const uint4* src = (const uint4*)wf;
    uint4* dst = (uint4*)smem;
#pragma unroll
    for (int i = 0; i < 3; i++) dst[threadIdx.x + i * 512] = src[threadIdx.x + i * 512];
  }
  __syncthreads();

  const __bf16* w1f = (const __bf16*)smem;
  const __bf16* w2f = (const __bf16*)(smem + 16384);
  const int wid = threadIdx.x >> 6;
  const int l   = threadIdx.x & 63;
  const int g   = l >> 4;    // lane group 0..3
  const int lr  = l & 15;    // lane row/col 0..15
  __bf16* h1   = (__bf16*)(smem + 24576 + wid * 4096);
  float*  attl = (float*)(smem + 57344 + wid * 128);

  // Per-lane bias/weight slices (constant across nodes) — hoisted.
  float b1v[4], b2v[4], w3v[4];
#pragma unroll
  for (int nt = 0; nt < 4; nt++) {
    b1v[nt] = b1g[nt * 16 + lr];
    b2v[nt] = b2g[nt * 16 + lr];
    w3v[nt] = w3g[nt * 16 + lr];
  }
  const float b3v = b3g[0];

  const int gw = blockIdx.x * (blockDim.x >> 6) + wid;
  const int nwaves = gridDim.x * (blockDim.x >> 6);

  for (int n = gw; n < N; n += nwaves) {
    const int node = video_nodes[n];
    const int deg  = neigh_deg[n];
    const float* ub = emb + node * 64;

    if (deg == 0) {           // fall back to own embedding (wave-uniform)
      out[n * 64 + l] = ub[l];
      continue;
    }
    const bool m1 = (deg > 16);   // wave-uniform: is the second row-tile live?

    // ---- gather neighbor embeddings directly into A-fragments (bf16) ----
    bf16x8 ef[2][2];
#pragma unroll
    for (int m = 0; m < 2; m++) {
      if (m == 0 || m1) {
        const int row = m * 16 + lr;
        const bool valid = (row < deg);
        int nidx = valid ? neigh_idx[n * 32 + row] : 0;
#pragma unroll
        for (int ks = 0; ks < 2; ks++) {
          float4 f0 = make_float4(0.f, 0.f, 0.f, 0.f), f1 = f0;
          if (valid) {
            const float* p = emb + nidx * 64 + ks * 32 + g * 8;
            f0 = *(const float4*)p;
            f1 = *(const float4*)(p + 4);
          }
          ef[m][ks] = cvt8(f0, f1);
        }
      }
    }
    // u fragments (rows identical across k => one frag per ks, shared by both m-tiles)
    bf16x8 uf[2];
#pragma unroll
    for (int ks = 0; ks < 2; ks++) {
      const float* p = ub + ks * 32 + g * 8;
      uf[ks] = cvt8(*(const float4*)p, *(const float4*)(p + 4));
    }

    // ---- layer 1: C1[32][64] = [E|u] @ W1 ----
    f32x4 acc[2][4];
#pragma unroll
    for (int m = 0; m < 2; m++)
#pragma unroll
      for (int nt = 0; nt < 4; nt++) acc[m][nt] = (f32x4){0.f, 0.f, 0.f, 0.f};

#pragma unroll
    for (int ks = 0; ks < 4; ks++) {
      bf16x8 a0 = (ks < 2) ? ef[0][ks] : uf[ks - 2];
#pragma unroll
      for (int nt = 0; nt < 4; nt++) {
        bf16x8 bb = *(const bf16x8*)(w1f + ((ks * 4 + nt) * 64 + l) * 8);
        MFMA16(acc[0][nt], a0, bb);
        if (m1) {
          bf16x8 a1 = (ks < 2) ? ef[1][ks] : uf[ks - 2];
          MFMA16(acc[1][nt], a1, bb);
        }
      }
    }

    // ---- relu + b1, write H1 to swizzled LDS (bf16) ----
#pragma unroll
    for (int m = 0; m < 2; m++) {
      if (m == 0 || m1) {
#pragma unroll
        for (int nt = 0; nt < 4; nt++) {
#pragma unroll
          for (int r = 0; r < 4; r++) {
            float h = fmaxf(acc[m][nt][r] + b1v[nt], 0.f);
            const int rw = m * 16 + g * 4 + r;
            const int j  = nt * 16 + lr;
            const int byte = rw * 128 + ((((j >> 3) ^ (rw & 7))) << 4) + (j & 7) * 2;
            *(__bf16*)((unsigned char*)h1 + byte) = (__bf16)h;
          }
        }
      }
    }
    asm volatile("s_waitcnt lgkmcnt(0)" ::: "memory");  // wave-internal LDS fence

    // ---- layer 2: C2[32][64] = H1 @ W2 ----
    f32x4 acc2[2][4];
#pragma unroll
    for (int m = 0; m < 2; m++)
#pragma unroll
      for (int nt = 0; nt < 4; nt++) acc2[m][nt] = (f32x4){0.f, 0.f, 0.f, 0.f};

#pragma unroll
    for (int ks = 0; ks < 2; ks++) {
      bf16x8 A20, A21;
      {
        const int row = lr;
        const int chunk = (ks * 4 + g) ^ (row & 7);
        A20 = *(const bf16x8*)((unsigned char*)h1 + row * 128 + chunk * 16);
      }
      if (m1) {
        const int row = 16 + lr;
        const int chunk = (ks * 4 + g) ^ (row & 7);
        A21 = *(const bf16x8*)((unsigned char*)h1 + row * 128 + chunk * 16);
      }
#pragma unroll
      for (int nt = 0; nt < 4; nt++) {
        bf16x8 bb = *(const bf16x8*)(w2f + ((ks * 4 + nt) * 64 + l) * 8);
        MFMA16(acc2[0][nt], A20, bb);
        if (m1) MFMA16(acc2[1][nt], A21, bb);
      }
    }

    // ---- scores s[k] = relu(C2+b2) . w3 + b3 ----
    float sv[2][4];
#pragma unroll
    for (int m = 0; m < 2; m++)
#pragma unroll
      for (int r = 0; r < 4; r++) {
        float sp = 0.f;
#pragma unroll
        for (int nt = 0; nt < 4; nt++)
          sp += fmaxf(acc2[m][nt][r] + b2v[nt], 0.f) * w3v[nt];
        sv[m][r] = sp;
      }
#pragma unroll
    for (int mask = 1; mask < 16; mask <<= 1)
#pragma unroll
      for (int m = 0; m < 2; m++)
#pragma unroll
        for (int r = 0; r < 4; r++) sv[m][r] += __shfl_xor(sv[m][r], mask);

    // ---- masked softmax over the 32 rows (lane holds 8 rows; groups cover all 32) ----
    float mx = -1e30f;
#pragma unroll
    for (int m = 0; m < 2; m++)
#pragma unroll
      for (int r = 0; r < 4; r++) {
        const int k = m * 16 + g * 4 + r;
        sv[m][r] = (k < deg) ? (sv[m][r] + b3v) : -1e30f;
        mx = fmaxf(mx, sv[m][r]);
      }
    mx = fmaxf(mx, __shfl_xor(mx, 16));
    mx = fmaxf(mx, __shfl_xor(mx, 32));

    float att[2][4];
    float sum = 0.f;
#pragma unroll
    for (int m = 0; m < 2; m++)
#pragma unroll
      for (int r = 0; r < 4; r++) {
        const int k = m * 16 + g * 4 + r;
        const float p = (k < deg) ? __expf(sv[m][r] - mx) : 0.f;
        att[m][r] = p;
        sum += p;
      }
    sum += __shfl_xor(sum, 16);
    sum += __shfl_xor(sum, 32);
    const float inv = 1.f / sum;

    if (lr == 0) {
#pragma unroll
      for (int m = 0; m < 2; m++)
#pragma unroll
        for (int r = 0; r < 4; r++) attl[m * 16 + g * 4 + r] = att[m][r] * inv;
    }
    asm volatile("s_waitcnt lgkmcnt(0)" ::: "memory");

    const float a0 = attl[lr];
    const float a1 = attl[16 + lr];

    // ---- out[d] = sum_k att[k] * e[k][d], fp32 accumulate from bf16 frags ----
    float o[16];
#pragma unroll
    for (int ks = 0; ks < 2; ks++)
#pragma unroll
      for (int j = 0; j < 8; j++) {
        float v = a0 * (float)ef[0][ks][j];
        if (m1) v += a1 * (float)ef[1][ks][j];
        o[ks * 8 + j] = v;
      }
#pragma unroll
    for (int mask = 1; mask < 16; mask <<= 1)
#pragma unroll
      for (int t = 0; t < 16; t++) o[t] += __shfl_xor(o[t], mask);

    if (lr == 0) {
      float* op = out + n * 64;
      *(float4*)(op + g * 8)          = make_float4(o[0], o[1], o[2], o[3]);
      *(float4*)(op + g * 8 + 4)      = make_float4(o[4], o[5], o[6], o[7]);
      *(float4*)(op + 32 + g * 8)     = make_float4(o[8], o[9], o[10], o[11]);
      *(float4*)(op + 36 + g * 8)     = make_float4(o[12], o[13], o[14], o[15]);
    }
  }
}

extern "C" void kernel_launch(void* const* d_in, const int* in_sizes, int n_in,
                              void* d_out, int out_size, void* d_ws, size_t ws_size,
                              hipStream_t stream) {
  const float* emb = (const float*)d_in[0];
  const float* W1  = (const float*)d_in[1];
  const float* b1  = (const float*)d_in[2];
  const float* W2  = (const float*)d_in[3];
  const float* b2  = (const float*)d_in[4];
  const float* w3  = (const float*)d_in[5];
  const float* b3  = (const float*)d_in[6];
  const int* vn = (const int*)d_in[7];
  const int* ni = (const int*)d_in[8];
  const int* nd = (const int*)d_in[9];
  float* out = (float*)d_out;
  const int N = in_sizes[7];
  __bf16* wf = (__bf16*)d_ws;   // needs 24576 B

  prep_frags<<<48, 256, 0, stream>>>(W1, W2, wf);
  graph_agg<<<512, 512, 0, stream>>>(emb, b1, b2, w3, b3, vn, ni, nd, wf, out, N);
}

// Round 2
// 86.024 us; speedup vs baseline: 1.6868x; 1.6868x over previous
//
#include <hip/hip_runtime.h>
#include <hip/hip_bf16.h>

typedef __bf16 bf16x8 __attribute__((ext_vector_type(8)));
typedef float  f32x4  __attribute__((ext_vector_type(4)));

#define MFMA32(acc, a, b) acc = __builtin_amdgcn_mfma_f32_16x16x32_bf16(a, b, acc, 0, 0, 0)

__device__ __forceinline__ bf16x8 cvt8(float4 a, float4 b) {
  bf16x8 r;
  r[0] = (__bf16)a.x; r[1] = (__bf16)a.y; r[2] = (__bf16)a.z; r[3] = (__bf16)a.w;
  r[4] = (__bf16)b.x; r[5] = (__bf16)b.y; r[6] = (__bf16)b.z; r[7] = (__bf16)b.w;
  return r;
}

// W1frag [ks=4][mt=4][lane][j=8]: A-frag of W1^T for 16x16x32:
//   = W1[(ks*32 + (lane>>4)*8 + j)][mt*16 + (lane&15)]
// W2frag [ks2=2][mt2=4][lane][j=8]: A-frag of W2^T with PERMUTED k-axis
//   rho(ks2,g,j) = (ks2*2 + (j>>2))*16 + g*4 + (j&3)   (g = lane>>4)
//   = W2[rho][mt2*16 + (lane&15)]
// The same rho permutation is used when building the B-frag from in-register
// layer-1 accumulators, so the MFMA reduction is correct.
__global__ void prep_frags(const float* __restrict__ W1,
                           const float* __restrict__ W2,
                           __bf16* __restrict__ wf) {
  int idx = blockIdx.x * 256 + threadIdx.x;
  if (idx < 8192) {
    int j = idx & 7, lane = (idx >> 3) & 63, mt = (idx >> 9) & 3, ks = idx >> 11;
    int i = ks * 32 + ((lane >> 4) << 3) + j;
    int col = mt * 16 + (lane & 15);
    wf[idx] = (__bf16)W1[i * 64 + col];
  } else if (idx < 12288) {
    int t = idx - 8192;
    int j = t & 7, lane = (t >> 3) & 63, mt2 = (t >> 9) & 3, ks2 = (t >> 11) & 1;
    int g = (lane >> 4) & 3;
    int rho = (ks2 * 2 + (j >> 2)) * 16 + g * 4 + (j & 3);
    wf[idx] = (__bf16)W2[rho * 64 + mt2 * 16 + (lane & 15)];
  }
}

// One wave per node, 256 threads = 4 waves/block.
// LDS: [0,16384) W1frag  [16384,24576) W2frag
//      [24576,24832) b1 f32  [24832,25088) b2 f32  [25088,25344) w3 f32
__global__ __launch_bounds__(256, 4) void graph_agg(
    const float* __restrict__ emb,
    const float* __restrict__ b1g,
    const float* __restrict__ b2g,
    const float* __restrict__ w3g,
    const float* __restrict__ b3g,
    const int* __restrict__ vn,
    const int* __restrict__ ni,
    const int* __restrict__ nd,
    const __bf16* __restrict__ wf,
    float* __restrict__ out,
    int N) {
  __shared__ __align__(16) unsigned char smem[25344];

  {
    const uint4* src = (const uint4*)wf;
    uint4* dst = (uint4*)smem;
#pragma unroll
    for (int i = 0; i < 6; i++) dst[threadIdx.x + i * 256] = src[threadIdx.x + i * 256];
    int t = threadIdx.x;
    if (t < 64) {
      ((float*)(smem + 24576))[t] = b1g[t];
      ((float*)(smem + 24832))[t] = b2g[t];
      ((float*)(smem + 25088))[t] = w3g[t];
    }
  }
  __syncthreads();

  const __bf16* w1f = (const __bf16*)smem;
  const __bf16* w2f = (const __bf16*)(smem + 16384);
  const int wid = threadIdx.x >> 6;
  const int l   = threadIdx.x & 63;
  const int g   = l >> 4;
  const int lr  = l & 15;
  const float b3v = b3g[0];

  const int gw = blockIdx.x * 4 + wid;
  const int nwaves = gridDim.x * 4;

  int n = gw;
  int node = 0, deg = 0, i0 = 0, i1 = 0;
  if (n < N) {
    node = vn[n]; deg = nd[n];
    i0 = ni[n * 32 + lr]; i1 = ni[n * 32 + 16 + lr];
  }

  for (; n < N; n += nwaves) {
    const int cn = node, cd = deg, ci0 = i0, ci1 = i1;
    {  // prefetch next iteration's scalars/indices
      int nn = n + nwaves; if (nn >= N) nn = n;
      node = vn[nn]; deg = nd[nn];
      i0 = ni[nn * 32 + lr]; i1 = ni[nn * 32 + 16 + lr];
    }
    const float* ub = emb + (long)cn * 64;

    if (cd == 0) {                 // no neighbors: copy own embedding
      out[(long)n * 64 + l] = ub[l];
      continue;
    }
    const bool m1 = (cd > 16);

    int boff = 24576;
    asm volatile("" : "+v"(boff));   // opaque: keep bias reads per-iteration (in LDS, not regs)
    const unsigned char* bb = smem + boff;

    // ---- gather: B-frags of X^T.  ef[nt][ks][j] = e[neigh[nt*16+lr]][ks*32+g*8+j]
    bf16x8 ef[2][2];
    bf16x8 uf[2];
    {
      const bool v = (lr < cd);
      const float* p = emb + (long)(v ? ci0 : cn) * 64 + g * 8;
      float4 a0 = *(const float4*)p,        a1 = *(const float4*)(p + 4);
      float4 c0 = *(const float4*)(p + 32), c1 = *(const float4*)(p + 36);
      if (!v) { a0 = a1 = c0 = c1 = make_float4(0.f, 0.f, 0.f, 0.f); }
      ef[0][0] = cvt8(a0, a1); ef[0][1] = cvt8(c0, c1);
    }
    if (m1) {
      const bool v = (16 + lr < cd);
      const float* p = emb + (long)(v ? ci1 : cn) * 64 + g * 8;
      float4 a0 = *(const float4*)p,        a1 = *(const float4*)(p + 4);
      float4 c0 = *(const float4*)(p + 32), c1 = *(const float4*)(p + 36);
      if (!v) { a0 = a1 = c0 = c1 = make_float4(0.f, 0.f, 0.f, 0.f); }
      ef[1][0] = cvt8(a0, a1); ef[1][1] = cvt8(c0, c1);
    }
    {
      const float* q = ub + g * 8;
      uf[0] = cvt8(*(const float4*)q,        *(const float4*)(q + 4));
      uf[1] = cvt8(*(const float4*)(q + 32), *(const float4*)(q + 36));
    }

    // ---- layer 1: C1t[64][32] = W1^T @ X^T  (acc init = b1 broadcast) ----
    f32x4 acc1[4][2];
#pragma unroll
    for (int mt = 0; mt < 4; mt++) {
      f32x4 bv = *(const f32x4*)(bb + (mt * 16 + g * 4) * 4);
      acc1[mt][0] = bv; acc1[mt][1] = bv;
    }
#pragma unroll
    for (int ks = 0; ks < 4; ks++) {
      bf16x8 xb0 = (ks < 2) ? ef[0][ks] : uf[ks - 2];
#pragma unroll
      for (int mt = 0; mt < 4; mt++) {
        bf16x8 wa = *(const bf16x8*)(w1f + ((ks * 4 + mt) * 64 + l) * 8);
        MFMA32(acc1[mt][0], wa, xb0);
        if (m1) {
          bf16x8 xb1 = (ks < 2) ? ef[1][ks] : uf[ks - 2];
          MFMA32(acc1[mt][1], wa, xb1);
        }
      }
    }

    // ---- relu -> bf16 B-frags for layer 2, permuted k-axis (in-register) ----
    bf16x8 hb[2][2];
#pragma unroll
    for (int ks2 = 0; ks2 < 2; ks2++) {
#pragma unroll
      for (int nt = 0; nt < 2; nt++) {
        if (nt == 0 || m1) {
          bf16x8 v;
#pragma unroll
          for (int j = 0; j < 8; j++) {
            const int mt = ks2 * 2 + (j >> 2), r = j & 3;
            v[j] = (__bf16)fmaxf(acc1[mt][nt][r], 0.f);
          }
          hb[ks2][nt] = v;
        }
      }
    }

    // ---- layer 2: C2t[64][32] = W2^T @ H1t (acc init = b2) ----
    f32x4 acc2[4][2];
#pragma unroll
    for (int mt2 = 0; mt2 < 4; mt2++) {
      f32x4 bv = *(const f32x4*)(bb + 256 + (mt2 * 16 + g * 4) * 4);
      acc2[mt2][0] = bv; acc2[mt2][1] = bv;
    }
#pragma unroll
    for (int ks2 = 0; ks2 < 2; ks2++) {
#pragma unroll
      for (int mt2 = 0; mt2 < 4; mt2++) {
        bf16x8 wa = *(const bf16x8*)(w2f + ((ks2 * 4 + mt2) * 64 + l) * 8);
        MFMA32(acc2[mt2][0], wa, hb[ks2][0]);
        if (m1) MFMA32(acc2[mt2][1], wa, hb[ks2][1]);
      }
    }

    // ---- scores: s[nb] = relu(C2t+b2) . w3 + b3 (partial over 16 in-lane h2 dims) ----
    float sv0 = 0.f, sv1 = 0.f;
    {
#pragma unroll
      for (int mt2 = 0; mt2 < 4; mt2++) {
        f32x4 wv = *(const f32x4*)(bb + 512 + (mt2 * 16 + g * 4) * 4);
#pragma unroll
        for (int r = 0; r < 4; r++) {
          sv0 += fmaxf(acc2[mt2][0][r], 0.f) * wv[r];
          if (m1) sv1 += fmaxf(acc2[mt2][1][r], 0.f) * wv[r];
        }
      }
    }
    sv0 += __shfl_xor(sv0, 16); sv0 += __shfl_xor(sv0, 32);
    if (m1) { sv1 += __shfl_xor(sv1, 16); sv1 += __shfl_xor(sv1, 32); }

    const bool v0 = (lr < cd);
    const bool v1 = m1 && (16 + lr < cd);
    sv0 = v0 ? (sv0 + b3v) : -1e30f;
    sv1 = v1 ? (sv1 + b3v) : -1e30f;

    float mx = fmaxf(sv0, sv1);
    mx = fmaxf(mx, __shfl_xor(mx, 1));
    mx = fmaxf(mx, __shfl_xor(mx, 2));
    mx = fmaxf(mx, __shfl_xor(mx, 4));
    mx = fmaxf(mx, __shfl_xor(mx, 8));

    float p0 = v0 ? __expf(sv0 - mx) : 0.f;
    float p1 = v1 ? __expf(sv1 - mx) : 0.f;
    float sum = p0 + p1;
    sum += __shfl_xor(sum, 1);
    sum += __shfl_xor(sum, 2);
    sum += __shfl_xor(sum, 4);
    sum += __shfl_xor(sum, 8);
    const float inv = 1.f / sum;
    const float a0 = p0 * inv, a1 = p1 * inv;

    // ---- out[d] = sum_k att[k]*e[k][d]: in-lane over nt, shfl-tree over lr ----
    float o[16];
#pragma unroll
    for (int ks = 0; ks < 2; ks++)
#pragma unroll
      for (int j = 0; j < 8; j++) {
        float v = a0 * (float)ef[0][ks][j];
        if (m1) v += a1 * (float)ef[1][ks][j];
        o[ks * 8 + j] = v;
      }
#pragma unroll
    for (int mask = 1; mask < 16; mask <<= 1)
#pragma unroll
      for (int t = 0; t < 16; t++) o[t] += __shfl_xor(o[t], mask);

    if (lr == 0) {
      float* op = out + (long)n * 64;
      *(float4*)(op + g * 8)      = make_float4(o[0],  o[1],  o[2],  o[3]);
      *(float4*)(op + g * 8 + 4)  = make_float4(o[4],  o[5],  o[6],  o[7]);
      *(float4*)(op + 32 + g * 8) = make_float4(o[8],  o[9],  o[10], o[11]);
      *(float4*)(op + 36 + g * 8) = make_float4(o[12], o[13], o[14], o[15]);
    }
  }
}

extern "C" void kernel_launch(void* const* d_in, const int* in_sizes, int n_in,
                              void* d_out, int out_size, void* d_ws, size_t ws_size,
                              hipStream_t stream) {
  const float* emb = (const float*)d_in[0];
  const float* W1  = (const float*)d_in[1];
  const float* b1  = (const float*)d_in[2];
  const float* W2  = (const float*)d_in[3];
  const float* b2  = (const float*)d_in[4];
  const float* w3  = (const float*)d_in[5];
  const float* b3  = (const float*)d_in[6];
  const int* vn = (const int*)d_in[7];
  const int* ni = (const int*)d_in[8];
  const int* nd = (const int*)d_in[9];
  float* out = (float*)d_out;
  const int N = in_sizes[7];
  __bf16* wf = (__bf16*)d_ws;   // 24576 B

  prep_frags<<<48, 256, 0, stream>>>(W1, W2, wf);
  graph_agg<<<1536, 256, 0, stream>>>(emb, b1, b2, w3, b3, vn, ni, nd, wf, out, N);
}